// Round 1
// baseline (1292.066 us; speedup 1.0000x reference)
//
#include <hip/hip_runtime.h>
#include <math.h>

#define NN 10000
#define NE 320000
#define DD 256
#define KSEL 8000

typedef unsigned int uint;

__device__ __forceinline__ void atomAddF(float* p, float v) {
    unsafeAtomicAdd(p, v);   // HW global_atomic_add_f32 (avoid CAS loop)
}

__device__ __forceinline__ uint encodeF(float f) {
    uint u = __float_as_uint(f);
    return (u & 0x80000000u) ? ~u : (u | 0x80000000u);
}
__device__ __forceinline__ float decodeF(uint u) {
    uint bits = (u & 0x80000000u) ? (u & 0x7FFFFFFFu) : ~u;
    return __uint_as_float(bits);
}

// ---------------- 1. scatter h rows into agg, count deg -------------------
__global__ __launch_bounds__(256) void scatter_h(
    const float* __restrict__ h, const int* __restrict__ ei,
    float* __restrict__ agg, float* __restrict__ deg) {
    int gt   = blockIdx.x * 256 + threadIdx.x;
    int edge = gt >> 6;
    int lane = gt & 63;
    if (edge >= NE) return;
    int src = ei[edge];
    int dst = ei[NE + edge];
    float4 v = *(const float4*)(h + (size_t)src * DD + lane * 4);
    float* o = agg + (size_t)dst * DD + lane * 4;
    atomAddF(o + 0, v.x);
    atomAddF(o + 1, v.y);
    atomAddF(o + 2, v.z);
    atomAddF(o + 3, v.w);
    if (lane == 0) atomAddF(deg + dst, 1.0f);
}

// ---------------- 2. x = relu(mean@W_l + h@W_r + b_l)  (in-place on agg) --
// A = [mean | h]  (K=512), W = [W_l ; W_r] (512x256). BM=32, BK=32, BN=256.
__global__ __launch_bounds__(256) void gemm_x(
    float* __restrict__ xbuf,          // holds agg on entry, x on exit
    const float* __restrict__ h,
    const float* __restrict__ W_l, const float* __restrict__ W_r,
    const float* __restrict__ b_l, const float* __restrict__ deg) {
    __shared__ float As[32][33];
    __shared__ float Ws[32][DD];
    const int t    = threadIdx.x;
    const int row0 = blockIdx.x * 32;
    const int arow = t >> 3, aseg = t & 7;     // A staging: 32 rows x 8 float4
    const int rg   = t >> 5, cg   = t & 31;    // micro-tile: 4 rows x (4+4) cols
    const int r0   = rg * 4;
    const int ca   = cg * 4;                   // cols ca..ca+3 and 128+ca..+3

    float acc[4][8];
#pragma unroll
    for (int i = 0; i < 4; i++)
#pragma unroll
        for (int j = 0; j < 8; j++) acc[i][j] = 0.f;

    const int  grow  = row0 + arow;
    const bool rowok = grow < NN;
    float invd = 1.0f;
    if (rowok) invd = 1.0f / fmaxf(deg[grow], 1.0f);

    for (int kb = 0; kb < 16; ++kb) {
        // --- stage A tile (32x32) ---
        float4 av = make_float4(0.f, 0.f, 0.f, 0.f);
        if (rowok) {
            if (kb < 8) {
                av = *(const float4*)(xbuf + (size_t)grow * DD + kb * 32 + aseg * 4);
                av.x *= invd; av.y *= invd; av.z *= invd; av.w *= invd;
            } else {
                av = *(const float4*)(h + (size_t)grow * DD + (kb - 8) * 32 + aseg * 4);
            }
        }
        As[arow][aseg * 4 + 0] = av.x;
        As[arow][aseg * 4 + 1] = av.y;
        As[arow][aseg * 4 + 2] = av.z;
        As[arow][aseg * 4 + 3] = av.w;
        // --- stage W tile (32x256): 2048 float4, 8 per thread ---
        const float* Wsrc = (kb < 8) ? (W_l + (size_t)kb * 32 * DD)
                                     : (W_r + (size_t)(kb - 8) * 32 * DD);
#pragma unroll
        for (int it = 0; it < 8; ++it) {
            int f  = it * 256 + t;
            int wk = f >> 6;
            int wc = (f & 63) * 4;
            *(float4*)(&Ws[wk][wc]) = *(const float4*)(Wsrc + wk * DD + wc);
        }
        __syncthreads();
        // --- compute ---
#pragma unroll
        for (int kk4 = 0; kk4 < 8; ++kk4) {
            float a[4][4];
#pragma unroll
            for (int i = 0; i < 4; i++) {
#pragma unroll
                for (int q = 0; q < 4; q++) a[i][q] = As[r0 + i][kk4 * 4 + q];
            }
#pragma unroll
            for (int kk = 0; kk < 4; ++kk) {
                float b[8];
                *(float4*)&b[0] = *(float4*)(&Ws[kk4 * 4 + kk][ca]);
                *(float4*)&b[4] = *(float4*)(&Ws[kk4 * 4 + kk][128 + ca]);
#pragma unroll
                for (int i = 0; i < 4; i++)
#pragma unroll
                    for (int j = 0; j < 8; j++)
                        acc[i][j] = fmaf(a[i][kk], b[j], acc[i][j]);
            }
        }
        __syncthreads();
    }
    // --- epilogue: + b_l, relu, store x (in place) ---
    float bl[8];
    *(float4*)&bl[0] = *(const float4*)(b_l + ca);
    *(float4*)&bl[4] = *(const float4*)(b_l + 128 + ca);
#pragma unroll
    for (int i = 0; i < 4; i++) {
        int rr = row0 + r0 + i;
        if (rr < NN) {
            float o[8];
#pragma unroll
            for (int j = 0; j < 8; j++) o[j] = fmaxf(acc[i][j] + bl[j], 0.f);
            *(float4*)(xbuf + (size_t)rr * DD + ca)       = *(float4*)&o[0];
            *(float4*)(xbuf + (size_t)rr * DD + 128 + ca) = *(float4*)&o[4];
        }
    }
}

// ---------------- 3. per-node scalars y = x@W_rel, c = x@W_gate, r = x@W_root
__global__ __launch_bounds__(256) void scalars_k(
    const float* __restrict__ x,
    const float* __restrict__ W_rel, const float* __restrict__ W_gate,
    const float* __restrict__ W_root,
    float* __restrict__ y, float* __restrict__ c, float* __restrict__ r) {
    int gt   = blockIdx.x * 256 + threadIdx.x;
    int node = gt >> 6, lane = gt & 63;
    if (node >= NN) return;
    float4 xv = *(const float4*)(x + (size_t)node * DD + lane * 4);
    float4 wr = *(const float4*)(W_rel + lane * 4);
    float4 wg = *(const float4*)(W_gate + lane * 4);
    float4 wo = *(const float4*)(W_root + lane * 4);
    float sy = xv.x * wr.x + xv.y * wr.y + xv.z * wr.z + xv.w * wr.w;
    float sc = xv.x * wg.x + xv.y * wg.y + xv.z * wg.z + xv.w * wg.w;
    float sr = xv.x * wo.x + xv.y * wo.y + xv.z * wo.z + xv.w * wo.w;
    for (int o = 32; o; o >>= 1) {
        sy += __shfl_xor(sy, o);
        sc += __shfl_xor(sc, o);
        sr += __shfl_xor(sr, o);
    }
    if (lane == 0) { y[node] = sy; c[node] = sc; r[node] = sr; }
}

// ---------------- 4. scatter scalar y along edges -------------------------
__global__ __launch_bounds__(256) void scatter_y(
    const float* __restrict__ y, const int* __restrict__ ei,
    float* __restrict__ sagg) {
    int e = blockIdx.x * 256 + threadIdx.x;
    if (e >= NE) return;
    atomAddF(sagg + ei[NE + e], y[ei[e]]);
}

// ---------------- 5. score + sortable key ---------------------------------
__global__ __launch_bounds__(256) void score_key(
    const float* __restrict__ sagg, const float* __restrict__ r,
    const float* __restrict__ b_rel,
    float* __restrict__ score, uint* __restrict__ key) {
    int i = blockIdx.x * 256 + threadIdx.x;
    if (i >= NN) return;
    float s  = tanhf(sagg[i] + b_rel[0] + r[i]);
    score[i] = s;
    key[i]   = encodeF(s);
}

// ---------------- 6. exact k-th largest via 4-round radix select ----------
__global__ __launch_bounds__(1024) void radix_select(
    const uint* __restrict__ key, uint* __restrict__ sel) {
    __shared__ uint hist[256];
    __shared__ uint sh_prefix, sh_need;
    uint prefix = 0, pmask = 0, need = KSEL;
    for (int shift = 24; shift >= 0; shift -= 8) {
        for (int i = threadIdx.x; i < 256; i += 1024) hist[i] = 0;
        __syncthreads();
        for (int i = threadIdx.x; i < NN; i += 1024) {
            uint k = key[i];
            if ((k & pmask) == prefix) atomicAdd(&hist[(k >> shift) & 255], 1u);
        }
        __syncthreads();
        if (threadIdx.x == 0) {
            uint nd = need;
            int  b;
            for (b = 255; b >= 0; b--) {
                uint cb = hist[b];
                if (nd <= cb) break;
                nd -= cb;
            }
            if (b < 0) b = 0;   // unreachable safety
            sh_prefix = prefix | ((uint)b << shift);
            sh_need   = nd;
        }
        __syncthreads();
        prefix = sh_prefix;
        need   = sh_need;
        pmask |= (0xFFu << shift);
        __syncthreads();
    }
    if (threadIdx.x == 0) { sel[0] = prefix; sel[1] = need; }
}

// ---------------- 7. max logit over (superset of) selected ----------------
__global__ __launch_bounds__(256) void max_logit(
    const float* __restrict__ score, const float* __restrict__ c,
    const uint* __restrict__ key, const uint* __restrict__ sel,
    uint* __restrict__ mEnc) {
    int  i = blockIdx.x * 256 + threadIdx.x;
    uint T = sel[0];
    float v = -INFINITY;
    if (i < NN && key[i] >= T) v = score[i] * c[i];
    for (int o = 32; o; o >>= 1) v = fmaxf(v, __shfl_xor(v, o));
    if ((threadIdx.x & 63) == 0) atomicMax(mEnc, encodeF(v));
}

// ---------------- 8. weighted reduction over selected set ----------------
__global__ __launch_bounds__(256) void reduce_out(
    const float* __restrict__ x, const float* __restrict__ score,
    const float* __restrict__ c, const uint* __restrict__ key,
    const uint* __restrict__ sel, const uint* __restrict__ mEnc,
    uint* __restrict__ ticket, float* __restrict__ numer,
    float* __restrict__ denom) {
    uint  T      = sel[0];
    uint  needEq = sel[1];
    float m      = decodeF(*mEnc);
    int lane = threadIdx.x & 63;
    int gw   = blockIdx.x * (256 >> 6) + (threadIdx.x >> 6);
    int nw   = gridDim.x * (256 >> 6);
    float4 np = make_float4(0.f, 0.f, 0.f, 0.f);
    float  dp = 0.f;
    for (int i = gw; i < NN; i += nw) {
        uint k = key[i];
        bool selm;
        if (k > T) {
            selm = true;
        } else if (k == T) {
            uint pos = 0;
            if (lane == 0) pos = atomicAdd(ticket, 1u);
            pos  = __shfl(pos, 0);
            selm = pos < needEq;
        } else {
            selm = false;
        }
        if (!selm) continue;
        float s  = score[i];
        float w  = expf(s * c[i] - m);
        dp += w;
        float  wsc = w * s;
        float4 xv  = *(const float4*)(x + (size_t)i * DD + lane * 4);
        np.x += wsc * xv.x;
        np.y += wsc * xv.y;
        np.z += wsc * xv.z;
        np.w += wsc * xv.w;
    }
    atomAddF(numer + lane * 4 + 0, np.x);
    atomAddF(numer + lane * 4 + 1, np.y);
    atomAddF(numer + lane * 4 + 2, np.z);
    atomAddF(numer + lane * 4 + 3, np.w);
    if (lane == 0) atomAddF(denom, dp);
}

// ---------------- 9. finalize ---------------------------------------------
__global__ __launch_bounds__(256) void finalize(
    const float* __restrict__ numer, const float* __restrict__ denom,
    float* __restrict__ out) {
    int i  = threadIdx.x;
    out[i] = numer[i] / denom[0];
}

extern "C" void kernel_launch(void* const* d_in, const int* in_sizes, int n_in,
                              void* d_out, int out_size, void* d_ws, size_t ws_size,
                              hipStream_t stream) {
    const float* h      = (const float*)d_in[0];
    const int*   ei     = (const int*)d_in[1];
    const float* W_l    = (const float*)d_in[2];
    const float* b_l    = (const float*)d_in[3];
    const float* W_r    = (const float*)d_in[4];
    const float* W_rel  = (const float*)d_in[5];
    const float* b_rel  = (const float*)d_in[6];
    const float* W_root = (const float*)d_in[7];
    const float* W_gate = (const float*)d_in[8];
    // const float* b_gate = (const float*)d_in[9];   // cancels in softmax
    float* out = (float*)d_out;

    // workspace layout
    float* agg   = (float*)d_ws;                 // N*D (agg, then x in place)
    float* deg   = agg + (size_t)NN * DD;        // N
    float* y     = deg + NN;                     // N
    float* cbuf  = y + NN;                       // N
    float* rbuf  = cbuf + NN;                    // N
    float* sagg  = rbuf + NN;                    // N
    float* score = sagg + NN;                    // N
    uint*  key   = (uint*)(score + NN);          // N
    float* numer = (float*)(key + NN);           // D
    float* denom = numer + DD;                   // 1
    uint*  mEnc  = (uint*)(denom + 1);           // 1
    uint*  tick  = mEnc + 1;                     // 1
    uint*  sel   = tick + 1;                     // 2
    size_t ws_used = (size_t)((char*)(sel + 2) - (char*)d_ws);

    hipMemsetAsync(d_ws, 0, ws_used, stream);

    scatter_h<<<(NE * 64) / 256, 256, 0, stream>>>(h, ei, agg, deg);
    gemm_x<<<(NN + 31) / 32, 256, 0, stream>>>(agg, h, W_l, W_r, b_l, deg);
    scalars_k<<<(NN * 64 + 255) / 256, 256, 0, stream>>>(agg, W_rel, W_gate, W_root,
                                                         y, cbuf, rbuf);
    scatter_y<<<(NE + 255) / 256, 256, 0, stream>>>(y, ei, sagg);
    score_key<<<(NN + 255) / 256, 256, 0, stream>>>(sagg, rbuf, b_rel, score, key);
    radix_select<<<1, 1024, 0, stream>>>(key, sel);
    max_logit<<<(NN + 255) / 256, 256, 0, stream>>>(score, cbuf, key, sel, mEnc);
    reduce_out<<<128, 256, 0, stream>>>(agg, score, cbuf, key, sel, mEnc,
                                        tick, numer, denom);
    finalize<<<1, 256, 0, stream>>>(numer, denom, out);
    (void)n_in; (void)in_sizes; (void)out_size; (void)ws_size;
}

// Round 2
// 281.116 us; speedup vs baseline: 4.5962x; 4.5962x over previous
//
#include <hip/hip_runtime.h>
#include <math.h>

#define NN 10000
#define NE 320000
#define DD 256
#define KSEL 8000

typedef unsigned int uint;

__device__ __forceinline__ void atomAddF(float* p, float v) {
    unsafeAtomicAdd(p, v);   // HW global_atomic_add_f32
}

__device__ __forceinline__ uint encodeF(float f) {
    uint u = __float_as_uint(f);
    return (u & 0x80000000u) ? ~u : (u | 0x80000000u);
}
__device__ __forceinline__ float decodeF(uint u) {
    uint bits = (u & 0x80000000u) ? (u & 0x7FFFFFFFu) : ~u;
    return __uint_as_float(bits);
}

// ---------------- 1. degree histogram (int atomics) -----------------------
__global__ __launch_bounds__(256) void count_deg(
    const int* __restrict__ ei, int* __restrict__ degi) {
    int e = blockIdx.x * 256 + threadIdx.x;
    if (e >= NE) return;
    atomicAdd(&degi[ei[NE + e]], 1);
}

// ---------------- 2. single-block prefix scan -> start/cursor/invdeg ------
__global__ __launch_bounds__(1024) void scan_start(
    const int* __restrict__ degi, int* __restrict__ start,
    int* __restrict__ cursor, float* __restrict__ invdeg) {
    __shared__ int partial[1024];
    const int t  = threadIdx.x;
    const int CH = (NN + 1023) / 1024;   // 10
    const int base = t * CH;
    int sum = 0;
#pragma unroll
    for (int i = 0; i < CH; i++) {
        int idx = base + i;
        if (idx < NN) sum += degi[idx];
    }
    partial[t] = sum;
    __syncthreads();
    for (int off = 1; off < 1024; off <<= 1) {
        int add = (t >= off) ? partial[t - off] : 0;
        __syncthreads();
        partial[t] += add;
        __syncthreads();
    }
    int run = partial[t] - sum;          // exclusive prefix of this chunk
#pragma unroll
    for (int i = 0; i < CH; i++) {
        int idx = base + i;
        if (idx < NN) {
            start[idx]  = run;
            cursor[idx] = run;
            int d = degi[idx];
            invdeg[idx] = 1.0f / fmaxf((float)d, 1.0f);
            run += d;
        }
    }
    if (t == 1023) start[NN] = NE;
}

// ---------------- 3. fill CSR (group edges by dst) ------------------------
__global__ __launch_bounds__(256) void fill_csr(
    const int* __restrict__ ei, int* __restrict__ cursor,
    int* __restrict__ csr) {
    int e = blockIdx.x * 256 + threadIdx.x;
    if (e >= NE) return;
    int pos = atomicAdd(&cursor[ei[NE + e]], 1);
    csr[pos] = ei[e];
}

// ---------------- 4. gather-aggregate: mean[i] = sum h[src] * invdeg ------
__global__ __launch_bounds__(256) void gather_mean(
    const float* __restrict__ h, const int* __restrict__ csr,
    const int* __restrict__ start, const float* __restrict__ invdeg,
    float* __restrict__ mean) {
    int node = blockIdx.x * 4 + (threadIdx.x >> 6);
    int lane = threadIdx.x & 63;
    if (node >= NN) return;
    int s = start[node], e = start[node + 1];
    const float* hp = h + (size_t)lane * 4;
    float4 a0 = make_float4(0.f, 0.f, 0.f, 0.f);
    float4 a1 = make_float4(0.f, 0.f, 0.f, 0.f);
    float4 a2 = make_float4(0.f, 0.f, 0.f, 0.f);
    float4 a3 = make_float4(0.f, 0.f, 0.f, 0.f);
    int j = s;
    for (; j + 4 <= e; j += 4) {
        int s0 = csr[j], s1 = csr[j + 1], s2 = csr[j + 2], s3 = csr[j + 3];
        float4 v0 = *(const float4*)(hp + (size_t)s0 * DD);
        float4 v1 = *(const float4*)(hp + (size_t)s1 * DD);
        float4 v2 = *(const float4*)(hp + (size_t)s2 * DD);
        float4 v3 = *(const float4*)(hp + (size_t)s3 * DD);
        a0.x += v0.x; a0.y += v0.y; a0.z += v0.z; a0.w += v0.w;
        a1.x += v1.x; a1.y += v1.y; a1.z += v1.z; a1.w += v1.w;
        a2.x += v2.x; a2.y += v2.y; a2.z += v2.z; a2.w += v2.w;
        a3.x += v3.x; a3.y += v3.y; a3.z += v3.z; a3.w += v3.w;
    }
    for (; j < e; j++) {
        int s0 = csr[j];
        float4 v0 = *(const float4*)(hp + (size_t)s0 * DD);
        a0.x += v0.x; a0.y += v0.y; a0.z += v0.z; a0.w += v0.w;
    }
    float id = invdeg[node];
    float4 m;
    m.x = (a0.x + a1.x + a2.x + a3.x) * id;
    m.y = (a0.y + a1.y + a2.y + a3.y) * id;
    m.z = (a0.z + a1.z + a2.z + a3.z) * id;
    m.w = (a0.w + a1.w + a2.w + a3.w) * id;
    *(float4*)(mean + (size_t)node * DD + lane * 4) = m;
}

// ---------------- 5. x = relu(mean@W_l + h@W_r + b_l) (in-place on mean) --
__global__ __launch_bounds__(256) void gemm_x(
    float* __restrict__ xbuf,          // mean on entry, x on exit
    const float* __restrict__ h,
    const float* __restrict__ W_l, const float* __restrict__ W_r,
    const float* __restrict__ b_l) {
    __shared__ float As[32][33];
    __shared__ float Ws[32][DD];
    const int t    = threadIdx.x;
    const int row0 = blockIdx.x * 32;
    const int arow = t >> 3, aseg = t & 7;
    const int rg   = t >> 5, cg   = t & 31;
    const int r0   = rg * 4;
    const int ca   = cg * 4;

    float acc[4][8];
#pragma unroll
    for (int i = 0; i < 4; i++)
#pragma unroll
        for (int j = 0; j < 8; j++) acc[i][j] = 0.f;

    const int  grow  = row0 + arow;
    const bool rowok = grow < NN;

    for (int kb = 0; kb < 16; ++kb) {
        float4 av = make_float4(0.f, 0.f, 0.f, 0.f);
        if (rowok) {
            if (kb < 8)
                av = *(const float4*)(xbuf + (size_t)grow * DD + kb * 32 + aseg * 4);
            else
                av = *(const float4*)(h + (size_t)grow * DD + (kb - 8) * 32 + aseg * 4);
        }
        As[arow][aseg * 4 + 0] = av.x;
        As[arow][aseg * 4 + 1] = av.y;
        As[arow][aseg * 4 + 2] = av.z;
        As[arow][aseg * 4 + 3] = av.w;
        const float* Wsrc = (kb < 8) ? (W_l + (size_t)kb * 32 * DD)
                                     : (W_r + (size_t)(kb - 8) * 32 * DD);
#pragma unroll
        for (int it = 0; it < 8; ++it) {
            int f  = it * 256 + t;
            int wk = f >> 6;
            int wc = (f & 63) * 4;
            *(float4*)(&Ws[wk][wc]) = *(const float4*)(Wsrc + wk * DD + wc);
        }
        __syncthreads();
#pragma unroll
        for (int kk4 = 0; kk4 < 8; ++kk4) {
            float a[4][4];
#pragma unroll
            for (int i = 0; i < 4; i++) {
#pragma unroll
                for (int q = 0; q < 4; q++) a[i][q] = As[r0 + i][kk4 * 4 + q];
            }
#pragma unroll
            for (int kk = 0; kk < 4; ++kk) {
                float b[8];
                *(float4*)&b[0] = *(float4*)(&Ws[kk4 * 4 + kk][ca]);
                *(float4*)&b[4] = *(float4*)(&Ws[kk4 * 4 + kk][128 + ca]);
#pragma unroll
                for (int i = 0; i < 4; i++)
#pragma unroll
                    for (int j = 0; j < 8; j++)
                        acc[i][j] = fmaf(a[i][kk], b[j], acc[i][j]);
            }
        }
        __syncthreads();
    }
    float bl[8];
    *(float4*)&bl[0] = *(const float4*)(b_l + ca);
    *(float4*)&bl[4] = *(const float4*)(b_l + 128 + ca);
#pragma unroll
    for (int i = 0; i < 4; i++) {
        int rr = row0 + r0 + i;
        if (rr < NN) {
            float o[8];
#pragma unroll
            for (int j = 0; j < 8; j++) o[j] = fmaxf(acc[i][j] + bl[j], 0.f);
            *(float4*)(xbuf + (size_t)rr * DD + ca)       = *(float4*)&o[0];
            *(float4*)(xbuf + (size_t)rr * DD + 128 + ca) = *(float4*)&o[4];
        }
    }
}

// ---------------- 6. per-node scalars y=x@W_rel, c=x@W_gate, r=x@W_root ---
__global__ __launch_bounds__(256) void scalars_k(
    const float* __restrict__ x,
    const float* __restrict__ W_rel, const float* __restrict__ W_gate,
    const float* __restrict__ W_root,
    float* __restrict__ y, float* __restrict__ c, float* __restrict__ r) {
    int gt   = blockIdx.x * 256 + threadIdx.x;
    int node = gt >> 6, lane = gt & 63;
    if (node >= NN) return;
    float4 xv = *(const float4*)(x + (size_t)node * DD + lane * 4);
    float4 wr = *(const float4*)(W_rel + lane * 4);
    float4 wg = *(const float4*)(W_gate + lane * 4);
    float4 wo = *(const float4*)(W_root + lane * 4);
    float sy = xv.x * wr.x + xv.y * wr.y + xv.z * wr.z + xv.w * wr.w;
    float sc = xv.x * wg.x + xv.y * wg.y + xv.z * wg.z + xv.w * wg.w;
    float sr = xv.x * wo.x + xv.y * wo.y + xv.z * wo.z + xv.w * wo.w;
    for (int o = 32; o; o >>= 1) {
        sy += __shfl_xor(sy, o);
        sc += __shfl_xor(sc, o);
        sr += __shfl_xor(sr, o);
    }
    if (lane == 0) { y[node] = sy; c[node] = sc; r[node] = sr; }
}

// ---------------- 7. gather y along CSR, score = tanh(.), sortable key ----
__global__ __launch_bounds__(256) void gather_score(
    const float* __restrict__ y, const float* __restrict__ r,
    const float* __restrict__ b_rel, const int* __restrict__ csr,
    const int* __restrict__ start,
    float* __restrict__ score, uint* __restrict__ key) {
    int gt   = blockIdx.x * 256 + threadIdx.x;
    int node = gt >> 6, lane = gt & 63;
    if (node >= NN) return;
    int s = start[node], e = start[node + 1];
    float acc = 0.f;
    for (int j = s + lane; j < e; j += 64) acc += y[csr[j]];
    for (int o = 32; o; o >>= 1) acc += __shfl_xor(acc, o);
    if (lane == 0) {
        float sc = tanhf(acc + b_rel[0] + r[node]);
        score[node] = sc;
        key[node]   = encodeF(sc);
    }
}

// ---------------- 8. exact k-th largest via 4-round radix select ----------
__global__ __launch_bounds__(1024) void radix_select(
    const uint* __restrict__ key, uint* __restrict__ sel) {
    __shared__ uint hist[256];
    __shared__ uint sh_prefix, sh_need;
    uint prefix = 0, pmask = 0, need = KSEL;
    for (int shift = 24; shift >= 0; shift -= 8) {
        for (int i = threadIdx.x; i < 256; i += 1024) hist[i] = 0;
        __syncthreads();
        for (int i = threadIdx.x; i < NN; i += 1024) {
            uint k = key[i];
            if ((k & pmask) == prefix) atomicAdd(&hist[(k >> shift) & 255], 1u);
        }
        __syncthreads();
        if (threadIdx.x == 0) {
            uint nd = need;
            int  b;
            for (b = 255; b >= 0; b--) {
                uint cb = hist[b];
                if (nd <= cb) break;
                nd -= cb;
            }
            if (b < 0) b = 0;
            sh_prefix = prefix | ((uint)b << shift);
            sh_need   = nd;
        }
        __syncthreads();
        prefix = sh_prefix;
        need   = sh_need;
        pmask |= (0xFFu << shift);
        __syncthreads();
    }
    if (threadIdx.x == 0) { sel[0] = prefix; sel[1] = need; }
}

// ---------------- 9. max logit over (superset of) selected ----------------
__global__ __launch_bounds__(256) void max_logit(
    const float* __restrict__ score, const float* __restrict__ c,
    const uint* __restrict__ key, const uint* __restrict__ sel,
    uint* __restrict__ mEnc) {
    int  i = blockIdx.x * 256 + threadIdx.x;
    uint T = sel[0];
    float v = -INFINITY;
    if (i < NN && key[i] >= T) v = score[i] * c[i];
    for (int o = 32; o; o >>= 1) v = fmaxf(v, __shfl_xor(v, o));
    if ((threadIdx.x & 63) == 0) atomicMax(mEnc, encodeF(v));
}

// ---------------- 10. weighted reduction over selected set ----------------
__global__ __launch_bounds__(256) void reduce_out(
    const float* __restrict__ x, const float* __restrict__ score,
    const float* __restrict__ c, const uint* __restrict__ key,
    const uint* __restrict__ sel, const uint* __restrict__ mEnc,
    uint* __restrict__ ticket, float* __restrict__ numer,
    float* __restrict__ denom) {
    uint  T      = sel[0];
    uint  needEq = sel[1];
    float m      = decodeF(*mEnc);
    int lane = threadIdx.x & 63;
    int gw   = blockIdx.x * (256 >> 6) + (threadIdx.x >> 6);
    int nw   = gridDim.x * (256 >> 6);
    float4 np = make_float4(0.f, 0.f, 0.f, 0.f);
    float  dp = 0.f;
    for (int i = gw; i < NN; i += nw) {
        uint k = key[i];
        bool selm;
        if (k > T) {
            selm = true;
        } else if (k == T) {
            uint pos = 0;
            if (lane == 0) pos = atomicAdd(ticket, 1u);
            pos  = __shfl(pos, 0);
            selm = pos < needEq;
        } else {
            selm = false;
        }
        if (!selm) continue;
        float s  = score[i];
        float w  = expf(s * c[i] - m);
        dp += w;
        float  wsc = w * s;
        float4 xv  = *(const float4*)(x + (size_t)i * DD + lane * 4);
        np.x += wsc * xv.x;
        np.y += wsc * xv.y;
        np.z += wsc * xv.z;
        np.w += wsc * xv.w;
    }
    atomAddF(numer + lane * 4 + 0, np.x);
    atomAddF(numer + lane * 4 + 1, np.y);
    atomAddF(numer + lane * 4 + 2, np.z);
    atomAddF(numer + lane * 4 + 3, np.w);
    if (lane == 0) atomAddF(denom, dp);
}

// ---------------- 11. finalize --------------------------------------------
__global__ __launch_bounds__(256) void finalize(
    const float* __restrict__ numer, const float* __restrict__ denom,
    float* __restrict__ out) {
    int i  = threadIdx.x;
    out[i] = numer[i] / denom[0];
}

extern "C" void kernel_launch(void* const* d_in, const int* in_sizes, int n_in,
                              void* d_out, int out_size, void* d_ws, size_t ws_size,
                              hipStream_t stream) {
    const float* h      = (const float*)d_in[0];
    const int*   ei     = (const int*)d_in[1];
    const float* W_l    = (const float*)d_in[2];
    const float* b_l    = (const float*)d_in[3];
    const float* W_r    = (const float*)d_in[4];
    const float* W_rel  = (const float*)d_in[5];
    const float* b_rel  = (const float*)d_in[6];
    const float* W_root = (const float*)d_in[7];
    const float* W_gate = (const float*)d_in[8];
    // b_gate (d_in[9]) cancels in softmax
    float* out = (float*)d_out;

    // ---- workspace layout ----
    float* mean   = (float*)d_ws;                  // N*D (mean, then x in place)
    int*   csr    = (int*)(mean + (size_t)NN * DD);// E
    int*   start  = csr + NE;                      // N+1
    int*   cursor = start + NN + 1;                // N
    float* invdeg = (float*)(cursor + NN);         // N
    float* y      = invdeg + NN;                   // N
    float* cbuf   = y + NN;                        // N
    float* rbuf   = cbuf + NN;                     // N
    float* score  = rbuf + NN;                     // N
    uint*  key    = (uint*)(score + NN);           // N
    // ---- zero-initialized tail (one small memset) ----
    int*   degi   = (int*)(key + NN);              // N
    float* numer  = (float*)(degi + NN);           // D
    float* denom  = numer + DD;                    // 1
    uint*  mEnc   = (uint*)(denom + 1);            // 1
    uint*  tick   = mEnc + 1;                      // 1
    uint*  sel    = tick + 1;                      // 2
    size_t zbytes = (size_t)((char*)(sel + 2) - (char*)degi);

    hipMemsetAsync(degi, 0, zbytes, stream);

    count_deg   <<<(NE + 255) / 256, 256, 0, stream>>>(ei, degi);
    scan_start  <<<1, 1024, 0, stream>>>(degi, start, cursor, invdeg);
    fill_csr    <<<(NE + 255) / 256, 256, 0, stream>>>(ei, cursor, csr);
    gather_mean <<<(NN + 3) / 4, 256, 0, stream>>>(h, csr, start, invdeg, mean);
    gemm_x      <<<(NN + 31) / 32, 256, 0, stream>>>(mean, h, W_l, W_r, b_l);
    scalars_k   <<<(NN * 64 + 255) / 256, 256, 0, stream>>>(mean, W_rel, W_gate,
                                                            W_root, y, cbuf, rbuf);
    gather_score<<<(NN * 64 + 255) / 256, 256, 0, stream>>>(y, rbuf, b_rel, csr,
                                                            start, score, key);
    radix_select<<<1, 1024, 0, stream>>>(key, sel);
    max_logit   <<<(NN + 255) / 256, 256, 0, stream>>>(score, cbuf, key, sel, mEnc);
    reduce_out  <<<128, 256, 0, stream>>>(mean, score, cbuf, key, sel, mEnc,
                                          tick, numer, denom);
    finalize    <<<1, 256, 0, stream>>>(numer, denom, out);
    (void)n_in; (void)in_sizes; (void)out_size; (void)ws_size;
}

// Round 3
// 272.957 us; speedup vs baseline: 4.7336x; 1.0299x over previous
//
#include <hip/hip_runtime.h>
#include <math.h>

#define NN 10000
#define NE 320000
#define DD 256
#define KSEL 8000

typedef unsigned int uint;

__device__ __forceinline__ void atomAddF(float* p, float v) {
    unsafeAtomicAdd(p, v);   // HW global_atomic_add_f32
}

__device__ __forceinline__ uint encodeF(float f) {
    uint u = __float_as_uint(f);
    return (u & 0x80000000u) ? ~u : (u | 0x80000000u);
}

// ---------------- 1. degree histogram (int atomics) -----------------------
__global__ __launch_bounds__(256) void count_deg(
    const int* __restrict__ ei, int* __restrict__ degi) {
    int e = blockIdx.x * 256 + threadIdx.x;
    if (e >= NE) return;
    atomicAdd(&degi[ei[NE + e]], 1);
}

// ---------------- 2. single-block prefix scan -> start/cursor/invdeg ------
__global__ __launch_bounds__(1024) void scan_start(
    const int* __restrict__ degi, int* __restrict__ start,
    int* __restrict__ cursor, float* __restrict__ invdeg) {
    __shared__ int partial[1024];
    const int t  = threadIdx.x;
    const int CH = (NN + 1023) / 1024;   // 10
    const int base = t * CH;
    int sum = 0;
#pragma unroll
    for (int i = 0; i < CH; i++) {
        int idx = base + i;
        if (idx < NN) sum += degi[idx];
    }
    partial[t] = sum;
    __syncthreads();
    for (int off = 1; off < 1024; off <<= 1) {
        int add = (t >= off) ? partial[t - off] : 0;
        __syncthreads();
        partial[t] += add;
        __syncthreads();
    }
    int run = partial[t] - sum;          // exclusive prefix of this chunk
#pragma unroll
    for (int i = 0; i < CH; i++) {
        int idx = base + i;
        if (idx < NN) {
            start[idx]  = run;
            cursor[idx] = run;
            int d = degi[idx];
            invdeg[idx] = 1.0f / fmaxf((float)d, 1.0f);
            run += d;
        }
    }
    if (t == 1023) start[NN] = NE;
}

// ---------------- 3. fill CSR (group edges by dst) ------------------------
__global__ __launch_bounds__(256) void fill_csr(
    const int* __restrict__ ei, int* __restrict__ cursor,
    int* __restrict__ csr) {
    int e = blockIdx.x * 256 + threadIdx.x;
    if (e >= NE) return;
    int pos = atomicAdd(&cursor[ei[NE + e]], 1);
    csr[pos] = ei[e];
}

// ---------------- 4. gather-aggregate: mean[i] = sum h[src] * invdeg ------
__global__ __launch_bounds__(256) void gather_mean(
    const float* __restrict__ h, const int* __restrict__ csr,
    const int* __restrict__ start, const float* __restrict__ invdeg,
    float* __restrict__ mean) {
    int node = blockIdx.x * 4 + (threadIdx.x >> 6);
    int lane = threadIdx.x & 63;
    if (node >= NN) return;
    int s = start[node], e = start[node + 1];
    const float* hp = h + (size_t)lane * 4;
    float4 a0 = make_float4(0.f, 0.f, 0.f, 0.f);
    float4 a1 = make_float4(0.f, 0.f, 0.f, 0.f);
    float4 a2 = make_float4(0.f, 0.f, 0.f, 0.f);
    float4 a3 = make_float4(0.f, 0.f, 0.f, 0.f);
    int j = s;
    for (; j + 4 <= e; j += 4) {
        int s0 = csr[j], s1 = csr[j + 1], s2 = csr[j + 2], s3 = csr[j + 3];
        float4 v0 = *(const float4*)(hp + (size_t)s0 * DD);
        float4 v1 = *(const float4*)(hp + (size_t)s1 * DD);
        float4 v2 = *(const float4*)(hp + (size_t)s2 * DD);
        float4 v3 = *(const float4*)(hp + (size_t)s3 * DD);
        a0.x += v0.x; a0.y += v0.y; a0.z += v0.z; a0.w += v0.w;
        a1.x += v1.x; a1.y += v1.y; a1.z += v1.z; a1.w += v1.w;
        a2.x += v2.x; a2.y += v2.y; a2.z += v2.z; a2.w += v2.w;
        a3.x += v3.x; a3.y += v3.y; a3.z += v3.z; a3.w += v3.w;
    }
    for (; j < e; j++) {
        int s0 = csr[j];
        float4 v0 = *(const float4*)(hp + (size_t)s0 * DD);
        a0.x += v0.x; a0.y += v0.y; a0.z += v0.z; a0.w += v0.w;
    }
    float id = invdeg[node];
    float4 m;
    m.x = (a0.x + a1.x + a2.x + a3.x) * id;
    m.y = (a0.y + a1.y + a2.y + a3.y) * id;
    m.z = (a0.z + a1.z + a2.z + a3.z) * id;
    m.w = (a0.w + a1.w + a2.w + a3.w) * id;
    *(float4*)(mean + (size_t)node * DD + lane * 4) = m;
}

// ---------------- 5. x = relu([mean|h]@[W_l;W_r] + b_l), fused y/c/r ------
// 32x32 tiles, 64-thread (1-wave) blocks, grid = 313*8 = 2504 waves
// (2.44 waves/SIMD -> ~81% packing vs 61% for the old 313x4-wave grid).
__global__ __launch_bounds__(64) void gemm_x(
    const float* __restrict__ mean, const float* __restrict__ h,
    const float* __restrict__ W_l, const float* __restrict__ W_r,
    const float* __restrict__ b_l,
    const float* __restrict__ W_rel, const float* __restrict__ W_gate,
    const float* __restrict__ W_root,
    float* __restrict__ xout, float* __restrict__ y,
    float* __restrict__ cvec, float* __restrict__ rvec) {
    __shared__ float As[32][34];   // 34-float stride: 8B-aligned b64, 2-way max
    __shared__ float Ws[32][36];   // 36-float stride: 16B-aligned b128, conflict-free
    const int t    = threadIdx.x;
    const int rt   = blockIdx.x >> 3, ct = blockIdx.x & 7;
    const int row0 = rt * 32, col0 = ct * 32;
    const int rg   = t >> 3, cg = t & 7;   // 4 rows x 4 cols micro-tile

    float acc[4][4];
#pragma unroll
    for (int i = 0; i < 4; i++)
#pragma unroll
        for (int j = 0; j < 4; j++) acc[i][j] = 0.f;

    for (int kb = 0; kb < 16; ++kb) {
        const int kcol = kb * 32 + cg * 4;   // global-k of this thread's stage seg
#pragma unroll
        for (int it = 0; it < 4; ++it) {
            const int r    = it * 8 + rg;
            const int grow = row0 + r;
            // --- A tile (32 rows x 32 k) ---
            float4 av = make_float4(0.f, 0.f, 0.f, 0.f);
            if (grow < NN) {
                av = (kb < 8)
                   ? *(const float4*)(mean + (size_t)grow * DD + kcol)
                   : *(const float4*)(h + (size_t)grow * DD + kcol - 256);
            }
            float2* ad = (float2*)&As[r][cg * 4];
            ad[0] = make_float2(av.x, av.y);
            ad[1] = make_float2(av.z, av.w);
            // --- W tile (32 k x 32 cols) ---
            const float* Wsrc = (kb < 8)
                ? (W_l + (size_t)(kb * 32 + r) * DD)
                : (W_r + (size_t)((kb - 8) * 32 + r) * DD);
            *(float4*)&Ws[r][cg * 4] = *(const float4*)(Wsrc + col0 + cg * 4);
        }
        __syncthreads();
#pragma unroll
        for (int kk4 = 0; kk4 < 8; ++kk4) {
            float a[4][4], b[4][4];
#pragma unroll
            for (int i = 0; i < 4; i++) {
                const float2* ap = (const float2*)&As[rg * 4 + i][kk4 * 4];
                float2 a0 = ap[0], a1 = ap[1];
                a[i][0] = a0.x; a[i][1] = a0.y; a[i][2] = a1.x; a[i][3] = a1.y;
            }
#pragma unroll
            for (int q = 0; q < 4; q++) {
                float4 bv = *(const float4*)&Ws[kk4 * 4 + q][cg * 4];
                b[q][0] = bv.x; b[q][1] = bv.y; b[q][2] = bv.z; b[q][3] = bv.w;
            }
#pragma unroll
            for (int q = 0; q < 4; q++)
#pragma unroll
                for (int i = 0; i < 4; i++)
#pragma unroll
                    for (int j = 0; j < 4; j++)
                        acc[i][j] = fmaf(a[i][q], b[q][j], acc[i][j]);
        }
        __syncthreads();
    }
    // --- epilogue: bias + relu + store x; fused partial y/c/r dots ---
    float4 bl = *(const float4*)(b_l    + col0 + cg * 4);
    float4 wl = *(const float4*)(W_rel  + col0 + cg * 4);
    float4 wg = *(const float4*)(W_gate + col0 + cg * 4);
    float4 wo = *(const float4*)(W_root + col0 + cg * 4);
#pragma unroll
    for (int i = 0; i < 4; i++) {
        const int grow = row0 + rg * 4 + i;    // uniform within 8-lane cg-group
        if (grow >= NN) continue;
        float o0 = fmaxf(acc[i][0] + bl.x, 0.f);
        float o1 = fmaxf(acc[i][1] + bl.y, 0.f);
        float o2 = fmaxf(acc[i][2] + bl.z, 0.f);
        float o3 = fmaxf(acc[i][3] + bl.w, 0.f);
        *(float4*)(xout + (size_t)grow * DD + col0 + cg * 4) =
            make_float4(o0, o1, o2, o3);
        float py = o0 * wl.x + o1 * wl.y + o2 * wl.z + o3 * wl.w;
        float pc = o0 * wg.x + o1 * wg.y + o2 * wg.z + o3 * wg.w;
        float pr = o0 * wo.x + o1 * wo.y + o2 * wo.z + o3 * wo.w;
#pragma unroll
        for (int off = 1; off < 8; off <<= 1) {   // reduce across cg lanes
            py += __shfl_xor(py, off);
            pc += __shfl_xor(pc, off);
            pr += __shfl_xor(pr, off);
        }
        if (cg == 0) {
            atomAddF(y + grow, py);
            atomAddF(cvec + grow, pc);
            atomAddF(rvec + grow, pr);
        }
    }
}

// ---------------- 6. gather y along CSR, score = tanh(.), sortable key ----
__global__ __launch_bounds__(256) void gather_score(
    const float* __restrict__ y, const float* __restrict__ r,
    const float* __restrict__ b_rel, const int* __restrict__ csr,
    const int* __restrict__ start,
    float* __restrict__ score, uint* __restrict__ key) {
    int gt   = blockIdx.x * 256 + threadIdx.x;
    int node = gt >> 6, lane = gt & 63;
    if (node >= NN) return;
    int s = start[node], e = start[node + 1];
    float acc = 0.f;
    for (int j = s + lane; j < e; j += 64) acc += y[csr[j]];
    for (int o = 32; o; o >>= 1) acc += __shfl_xor(acc, o);
    if (lane == 0) {
        float sc = tanhf(acc + b_rel[0] + r[node]);
        score[node] = sc;
        key[node]   = encodeF(sc);
    }
}

// ---------------- 7. radix select (exact k-th) + fused max-logit ----------
__global__ __launch_bounds__(1024) void radix_select(
    const uint* __restrict__ key, const float* __restrict__ score,
    const float* __restrict__ cvec,
    uint* __restrict__ sel, float* __restrict__ mval) {
    __shared__ uint  hist[256];
    __shared__ uint  ssum[256];
    __shared__ uint  sh_prefix, sh_need;
    __shared__ float wmax[16];
    const int t = threadIdx.x;
    uint prefix = 0, pmask = 0, need = KSEL;
    for (int shift = 24; shift >= 0; shift -= 8) {
        if (t < 256) hist[t] = 0;
        __syncthreads();
        for (int i = t; i < NN; i += 1024) {
            uint k = key[i];
            if ((k & pmask) == prefix) atomicAdd(&hist[(k >> shift) & 255], 1u);
        }
        __syncthreads();
        if (t < 256) ssum[t] = hist[t];
        __syncthreads();
        for (int off = 1; off < 256; off <<= 1) {   // parallel suffix sum
            uint add = 0;
            if (t < 256 && t + off < 256) add = ssum[t + off];
            __syncthreads();
            if (t < 256) ssum[t] += add;
            __syncthreads();
        }
        if (t < 256) {
            uint hi = ssum[t];
            uint lo = (t < 255) ? ssum[t + 1] : 0u;
            if (need <= hi && need > lo) {
                sh_prefix = prefix | ((uint)t << shift);
                sh_need   = need - lo;
            }
        }
        __syncthreads();
        prefix = sh_prefix;
        need   = sh_need;
        pmask |= (0xFFu << shift);
        __syncthreads();
    }
    // fused: max logit over superset {key >= prefix}
    float v = -INFINITY;
    for (int i = t; i < NN; i += 1024)
        if (key[i] >= prefix) v = fmaxf(v, score[i] * cvec[i]);
    for (int o = 32; o; o >>= 1) v = fmaxf(v, __shfl_xor(v, o));
    if ((t & 63) == 0) wmax[t >> 6] = v;
    __syncthreads();
    if (t == 0) {
        float m = wmax[0];
#pragma unroll
        for (int w = 1; w < 16; w++) m = fmaxf(m, wmax[w]);
        sel[0]  = prefix;
        sel[1]  = need;
        mval[0] = m;
    }
}

// ---------------- 8. weighted reduction over selected set ----------------
__global__ __launch_bounds__(256) void reduce_out(
    const float* __restrict__ x, const float* __restrict__ score,
    const float* __restrict__ c, const uint* __restrict__ key,
    const uint* __restrict__ sel, const float* __restrict__ mval,
    uint* __restrict__ ticket, float* __restrict__ numer,
    float* __restrict__ denom) {
    uint  T      = sel[0];
    uint  needEq = sel[1];
    float m      = mval[0];
    int lane = threadIdx.x & 63;
    int gw   = blockIdx.x * (256 >> 6) + (threadIdx.x >> 6);
    int nw   = gridDim.x * (256 >> 6);
    float4 np = make_float4(0.f, 0.f, 0.f, 0.f);
    float  dp = 0.f;
    for (int i = gw; i < NN; i += nw) {
        uint k = key[i];
        bool selm;
        if (k > T) {
            selm = true;
        } else if (k == T) {
            uint pos = 0;
            if (lane == 0) pos = atomicAdd(ticket, 1u);
            pos  = __shfl(pos, 0);
            selm = pos < needEq;
        } else {
            selm = false;
        }
        if (!selm) continue;
        float s  = score[i];
        float w  = expf(s * c[i] - m);
        dp += w;
        float  wsc = w * s;
        float4 xv  = *(const float4*)(x + (size_t)i * DD + lane * 4);
        np.x += wsc * xv.x;
        np.y += wsc * xv.y;
        np.z += wsc * xv.z;
        np.w += wsc * xv.w;
    }
    atomAddF(numer + lane * 4 + 0, np.x);
    atomAddF(numer + lane * 4 + 1, np.y);
    atomAddF(numer + lane * 4 + 2, np.z);
    atomAddF(numer + lane * 4 + 3, np.w);
    if (lane == 0) atomAddF(denom, dp);
}

// ---------------- 9. finalize ---------------------------------------------
__global__ __launch_bounds__(256) void finalize(
    const float* __restrict__ numer, const float* __restrict__ denom,
    float* __restrict__ out) {
    int i  = threadIdx.x;
    out[i] = numer[i] / denom[0];
}

extern "C" void kernel_launch(void* const* d_in, const int* in_sizes, int n_in,
                              void* d_out, int out_size, void* d_ws, size_t ws_size,
                              hipStream_t stream) {
    const float* h      = (const float*)d_in[0];
    const int*   ei     = (const int*)d_in[1];
    const float* W_l    = (const float*)d_in[2];
    const float* b_l    = (const float*)d_in[3];
    const float* W_r    = (const float*)d_in[4];
    const float* W_rel  = (const float*)d_in[5];
    const float* b_rel  = (const float*)d_in[6];
    const float* W_root = (const float*)d_in[7];
    const float* W_gate = (const float*)d_in[8];
    // b_gate (d_in[9]) cancels in softmax
    float* out = (float*)d_out;

    // ---- workspace layout ----
    float* mean   = (float*)d_ws;                   // N*D
    float* xbuf   = mean + (size_t)NN * DD;         // N*D
    int*   csr    = (int*)(xbuf + (size_t)NN * DD); // E
    int*   start  = csr + NE;                       // N+1
    int*   cursor = start + NN + 1;                 // N
    float* invdeg = (float*)(cursor + NN);          // N
    float* score  = invdeg + NN;                    // N
    uint*  key    = (uint*)(score + NN);            // N
    // ---- zero-initialized tail (one small memset) ----
    int*   degi   = (int*)(key + NN);               // N
    float* y      = (float*)(degi + NN);            // N
    float* cbuf   = y + NN;                         // N
    float* rbuf   = cbuf + NN;                      // N
    float* numer  = rbuf + NN;                      // D
    float* denom  = numer + DD;                     // 1
    float* mval   = denom + 1;                      // 1
    uint*  tick   = (uint*)(mval + 1);              // 1
    uint*  sel    = tick + 1;                       // 2
    size_t zbytes = (size_t)((char*)(sel + 2) - (char*)degi);

    hipMemsetAsync(degi, 0, zbytes, stream);

    count_deg   <<<(NE + 255) / 256, 256, 0, stream>>>(ei, degi);
    scan_start  <<<1, 1024, 0, stream>>>(degi, start, cursor, invdeg);
    fill_csr    <<<(NE + 255) / 256, 256, 0, stream>>>(ei, cursor, csr);
    gather_mean <<<(NN + 3) / 4, 256, 0, stream>>>(h, csr, start, invdeg, mean);
    gemm_x      <<<313 * 8, 64, 0, stream>>>(mean, h, W_l, W_r, b_l,
                                             W_rel, W_gate, W_root,
                                             xbuf, y, cbuf, rbuf);
    gather_score<<<(NN * 64 + 255) / 256, 256, 0, stream>>>(y, rbuf, b_rel, csr,
                                                            start, score, key);
    radix_select<<<1, 1024, 0, stream>>>(key, score, cbuf, sel, mval);
    reduce_out  <<<128, 256, 0, stream>>>(xbuf, score, cbuf, key, sel, mval,
                                          tick, numer, denom);
    finalize    <<<1, 256, 0, stream>>>(numer, denom, out);
    (void)n_in; (void)in_sizes; (void)out_size; (void)ws_size;
}

// Round 4
// 227.578 us; speedup vs baseline: 5.6775x; 1.1994x over previous
//
#include <hip/hip_runtime.h>
#include <math.h>

#define NN 10000
#define NE 320000
#define DD 256
#define KSEL 8000
#define KK 512

typedef unsigned int uint;
typedef unsigned short ushort;
typedef __attribute__((ext_vector_type(8))) short short8;   // 8 bf16 (4 VGPR)
typedef __attribute__((ext_vector_type(4))) float f32x4;
typedef __attribute__((ext_vector_type(4))) ushort us4;
typedef __attribute__((ext_vector_type(8))) ushort us8;

__device__ __forceinline__ void atomAddF(float* p, float v) {
    unsafeAtomicAdd(p, v);   // HW global_atomic_add_f32
}

__device__ __forceinline__ uint encodeF(float f) {
    uint u = __float_as_uint(f);
    return (u & 0x80000000u) ? ~u : (u | 0x80000000u);
}

__device__ __forceinline__ ushort f2bf(float f) {   // round-to-nearest-even
    uint u = __float_as_uint(f);
    u += 0x7FFFu + ((u >> 16) & 1u);
    return (ushort)(u >> 16);
}

// ---------------- 1. degree histogram (int atomics) -----------------------
__global__ __launch_bounds__(256) void count_deg(
    const int* __restrict__ ei, int* __restrict__ degi) {
    int e = blockIdx.x * 256 + threadIdx.x;
    if (e >= NE) return;
    atomicAdd(&degi[ei[NE + e]], 1);
}

// ---------------- 2. single-block prefix scan -> start/cursor/invdeg ------
__global__ __launch_bounds__(1024) void scan_start(
    const int* __restrict__ degi, int* __restrict__ start,
    int* __restrict__ cursor, float* __restrict__ invdeg) {
    __shared__ int partial[1024];
    const int t  = threadIdx.x;
    const int CH = (NN + 1023) / 1024;   // 10
    const int base = t * CH;
    int sum = 0;
#pragma unroll
    for (int i = 0; i < CH; i++) {
        int idx = base + i;
        if (idx < NN) sum += degi[idx];
    }
    partial[t] = sum;
    __syncthreads();
    for (int off = 1; off < 1024; off <<= 1) {
        int add = (t >= off) ? partial[t - off] : 0;
        __syncthreads();
        partial[t] += add;
        __syncthreads();
    }
    int run = partial[t] - sum;
#pragma unroll
    for (int i = 0; i < CH; i++) {
        int idx = base + i;
        if (idx < NN) {
            start[idx]  = run;
            cursor[idx] = run;
            int d = degi[idx];
            invdeg[idx] = 1.0f / fmaxf((float)d, 1.0f);
            run += d;
        }
    }
    if (t == 1023) start[NN] = NE;
}

// ---------------- 3. fill CSR (group edges by dst) ------------------------
__global__ __launch_bounds__(256) void fill_csr(
    const int* __restrict__ ei, int* __restrict__ cursor,
    int* __restrict__ csr) {
    int e = blockIdx.x * 256 + threadIdx.x;
    if (e >= NE) return;
    int pos = atomicAdd(&cursor[ei[NE + e]], 1);
    csr[pos] = ei[e];
}

// ---------------- 4a. cast h -> bf16 into A cols 256..511 -----------------
__global__ __launch_bounds__(256) void cast_h(
    const float* __restrict__ h, ushort* __restrict__ Ab) {
    int idx = blockIdx.x * 256 + threadIdx.x;          // NN*64 quads
    if (idx >= NN * 64) return;
    int node = idx >> 6, seg = (idx & 63) * 4;
    float4 v = *(const float4*)(h + (size_t)node * DD + seg);
    us4 o;
    o[0] = f2bf(v.x); o[1] = f2bf(v.y); o[2] = f2bf(v.z); o[3] = f2bf(v.w);
    *(us4*)(Ab + (size_t)node * KK + 256 + seg) = o;
}

// ---------------- 4b. cast+transpose [W_l;W_r] -> Wt[256][512] bf16 -------
__global__ __launch_bounds__(256) void cast_W(
    const float* __restrict__ W_l, const float* __restrict__ W_r,
    ushort* __restrict__ Wt) {
    int idx = blockIdx.x * 256 + threadIdx.x;          // k*256+n, coalesced read
    if (idx >= KK * DD) return;
    int k = idx >> 8, n = idx & 255;
    float v = (k < 256) ? W_l[(size_t)k * DD + n] : W_r[(size_t)(k - 256) * DD + n];
    Wt[(size_t)n * KK + k] = f2bf(v);
}

// ---------------- 5. gather-aggregate (bf16 reads) -> bf16 mean -----------
__global__ __launch_bounds__(256) void gather_mean(
    ushort* __restrict__ Ab, const int* __restrict__ csr,
    const int* __restrict__ start, const float* __restrict__ invdeg) {
    int node = blockIdx.x * 4 + (threadIdx.x >> 6);
    int lane = threadIdx.x & 63;
    if (node >= NN) return;
    int s = start[node], e = start[node + 1];
    const ushort* hb = Ab + 256 + lane * 4;            // h half of A
    float a0 = 0.f, a1 = 0.f, a2 = 0.f, a3 = 0.f;
    float b0 = 0.f, b1 = 0.f, b2 = 0.f, b3 = 0.f;
    int j = s;
    for (; j + 2 <= e; j += 2) {
        int s0 = csr[j], s1 = csr[j + 1];
        uint2 v0 = *(const uint2*)(hb + (size_t)s0 * KK);
        uint2 v1 = *(const uint2*)(hb + (size_t)s1 * KK);
        a0 += __uint_as_float(v0.x << 16);
        a1 += __uint_as_float(v0.x & 0xFFFF0000u);
        a2 += __uint_as_float(v0.y << 16);
        a3 += __uint_as_float(v0.y & 0xFFFF0000u);
        b0 += __uint_as_float(v1.x << 16);
        b1 += __uint_as_float(v1.x & 0xFFFF0000u);
        b2 += __uint_as_float(v1.y << 16);
        b3 += __uint_as_float(v1.y & 0xFFFF0000u);
    }
    for (; j < e; j++) {
        uint2 v0 = *(const uint2*)(hb + (size_t)csr[j] * KK);
        a0 += __uint_as_float(v0.x << 16);
        a1 += __uint_as_float(v0.x & 0xFFFF0000u);
        a2 += __uint_as_float(v0.y << 16);
        a3 += __uint_as_float(v0.y & 0xFFFF0000u);
    }
    float id = invdeg[node];
    us4 m;
    m[0] = f2bf((a0 + b0) * id);
    m[1] = f2bf((a1 + b1) * id);
    m[2] = f2bf((a2 + b2) * id);
    m[3] = f2bf((a3 + b3) * id);
    *(us4*)(Ab + (size_t)node * KK + lane * 4) = m;    // mean half of A
}

// ---------------- 6. MFMA GEMM: x = relu(A@Wt^T + b_l), fused y/c/r -------
// A bf16 [NN][512], Wt bf16 [256][512]. BM=32, BN=256, 4 waves (32x64 each).
__global__ __launch_bounds__(256) void gemm_x(
    const ushort* __restrict__ Ab, const ushort* __restrict__ Wt,
    const float* __restrict__ b_l,
    const float* __restrict__ W_rel, const float* __restrict__ W_gate,
    const float* __restrict__ W_root,
    float* __restrict__ xout, float* __restrict__ y,
    float* __restrict__ cvec, float* __restrict__ rvec) {
    __shared__ ushort Asm[2][32][40];    // +8 pad: 2-way banks max
    __shared__ ushort Bsm[2][256][40];
    const int t    = threadIdx.x;
    const int row0 = blockIdx.x * 32;
    const int wid  = t >> 6, lane = t & 63;
    const int l15  = lane & 15, g = lane >> 4;

    f32x4 acc[2][4];
#pragma unroll
    for (int fi = 0; fi < 2; fi++)
#pragma unroll
        for (int fj = 0; fj < 4; fj++) acc[fi][fj] = (f32x4)0.f;

    const int  arow = t >> 3, akseg = (t & 7) * 4;     // A: 8B/thread
    const bool aok  = (row0 + arow) < NN;
    const ushort* aptr = Ab + (size_t)(row0 + arow) * KK + akseg;
    const ushort* bptr = Wt + (size_t)t * KK;          // Bt: 64B/thread

    us4 areg = {0, 0, 0, 0};
    us8 breg[4];
    if (aok) areg = *(const us4*)(aptr);
#pragma unroll
    for (int jj = 0; jj < 4; jj++) breg[jj] = *(const us8*)(bptr + jj * 8);
    *(us4*)&Asm[0][arow][akseg] = areg;
#pragma unroll
    for (int jj = 0; jj < 4; jj++) *(us8*)&Bsm[0][t][jj * 8] = breg[jj];
    __syncthreads();

    for (int ks = 0; ks < 16; ++ks) {
        const int cur = ks & 1;
        if (ks < 15) {                               // issue next-step loads
            const int k0 = (ks + 1) * 32;
            if (aok) areg = *(const us4*)(aptr + k0);
#pragma unroll
            for (int jj = 0; jj < 4; jj++) breg[jj] = *(const us8*)(bptr + k0 + jj * 8);
        }
        short8 af0 = *(const short8*)&Asm[cur][l15][g * 8];
        short8 af1 = *(const short8*)&Asm[cur][16 + l15][g * 8];
#pragma unroll
        for (int fj = 0; fj < 4; fj++) {
            short8 bf = *(const short8*)&Bsm[cur][wid * 64 + fj * 16 + l15][g * 8];
            acc[0][fj] = __builtin_amdgcn_mfma_f32_16x16x32_bf16(af0, bf, acc[0][fj], 0, 0, 0);
            acc[1][fj] = __builtin_amdgcn_mfma_f32_16x16x32_bf16(af1, bf, acc[1][fj], 0, 0, 0);
        }
        if (ks < 15) {                               // write next buffer
            const int nb = cur ^ 1;
            *(us4*)&Asm[nb][arow][akseg] = areg;
#pragma unroll
            for (int jj = 0; jj < 4; jj++) *(us8*)&Bsm[nb][t][jj * 8] = breg[jj];
        }
        __syncthreads();
    }

    // epilogue: bias + relu + store x; fused y/c/r dots (D layout:
    // col = wcol0+fj*16+l15, row = row0+fi*16+g*4+r)
    const int wcol0 = wid * 64;
    float bl[4], wl[4], wg[4], wo[4];
#pragma unroll
    for (int fj = 0; fj < 4; fj++) {
        int col = wcol0 + fj * 16 + l15;
        bl[fj] = b_l[col]; wl[fj] = W_rel[col];
        wg[fj] = W_gate[col]; wo[fj] = W_root[col];
    }
#pragma unroll
    for (int fi = 0; fi < 2; fi++) {
#pragma unroll
        for (int r = 0; r < 4; r++) {
            int row = row0 + fi * 16 + g * 4 + r;
            if (row >= NN) continue;
            float py = 0.f, pc = 0.f, pr = 0.f;
#pragma unroll
            for (int fj = 0; fj < 4; fj++) {
                float v = fmaxf(acc[fi][fj][r] + bl[fj], 0.f);
                xout[(size_t)row * DD + wcol0 + fj * 16 + l15] = v;
                py = fmaf(v, wl[fj], py);
                pc = fmaf(v, wg[fj], pc);
                pr = fmaf(v, wo[fj], pr);
            }
#pragma unroll
            for (int off = 1; off < 16; off <<= 1) {   // reduce 16-lane group
                py += __shfl_xor(py, off);
                pc += __shfl_xor(pc, off);
                pr += __shfl_xor(pr, off);
            }
            if (l15 == 0) {
                atomAddF(y + row, py);
                atomAddF(cvec + row, pc);
                atomAddF(rvec + row, pr);
            }
        }
    }
}

// ---------------- 7. gather y along CSR, score = tanh(.), sortable key ----
__global__ __launch_bounds__(256) void gather_score(
    const float* __restrict__ y, const float* __restrict__ r,
    const float* __restrict__ b_rel, const int* __restrict__ csr,
    const int* __restrict__ start,
    float* __restrict__ score, uint* __restrict__ key) {
    int gt   = blockIdx.x * 256 + threadIdx.x;
    int node = gt >> 6, lane = gt & 63;
    if (node >= NN) return;
    int s = start[node], e = start[node + 1];
    float acc = 0.f;
    for (int j = s + lane; j < e; j += 64) acc += y[csr[j]];
    for (int o = 32; o; o >>= 1) acc += __shfl_xor(acc, o);
    if (lane == 0) {
        float sc = tanhf(acc + b_rel[0] + r[node]);
        score[node] = sc;
        key[node]   = encodeF(sc);
    }
}

// ---------------- 8. radix select (exact k-th) + fused max-logit ----------
__global__ __launch_bounds__(1024) void radix_select(
    const uint* __restrict__ key, const float* __restrict__ score,
    const float* __restrict__ cvec,
    uint* __restrict__ sel, float* __restrict__ mval) {
    __shared__ uint  hist[256];
    __shared__ uint  ssum[256];
    __shared__ uint  sh_prefix, sh_need;
    __shared__ float wmax[16];
    const int t = threadIdx.x;
    uint prefix = 0, pmask = 0, need = KSEL;
    for (int shift = 24; shift >= 0; shift -= 8) {
        if (t < 256) hist[t] = 0;
        __syncthreads();
        for (int i = t; i < NN; i += 1024) {
            uint k = key[i];
            if ((k & pmask) == prefix) atomicAdd(&hist[(k >> shift) & 255], 1u);
        }
        __syncthreads();
        if (t < 256) ssum[t] = hist[t];
        __syncthreads();
        for (int off = 1; off < 256; off <<= 1) {
            uint add = 0;
            if (t < 256 && t + off < 256) add = ssum[t + off];
            __syncthreads();
            if (t < 256) ssum[t] += add;
            __syncthreads();
        }
        if (t < 256) {
            uint hi = ssum[t];
            uint lo = (t < 255) ? ssum[t + 1] : 0u;
            if (need <= hi && need > lo) {
                sh_prefix = prefix | ((uint)t << shift);
                sh_need   = need - lo;
            }
        }
        __syncthreads();
        prefix = sh_prefix;
        need   = sh_need;
        pmask |= (0xFFu << shift);
        __syncthreads();
    }
    float v = -INFINITY;
    for (int i = t; i < NN; i += 1024)
        if (key[i] >= prefix) v = fmaxf(v, score[i] * cvec[i]);
    for (int o = 32; o; o >>= 1) v = fmaxf(v, __shfl_xor(v, o));
    if ((t & 63) == 0) wmax[t >> 6] = v;
    __syncthreads();
    if (t == 0) {
        float m = wmax[0];
#pragma unroll
        for (int w = 1; w < 16; w++) m = fmaxf(m, wmax[w]);
        sel[0]  = prefix;
        sel[1]  = need;
        mval[0] = m;
    }
}

// ---------------- 9. weighted reduction over selected set ----------------
__global__ __launch_bounds__(256) void reduce_out(
    const float* __restrict__ x, const float* __restrict__ score,
    const float* __restrict__ c, const uint* __restrict__ key,
    const uint* __restrict__ sel, const float* __restrict__ mval,
    uint* __restrict__ ticket, float* __restrict__ numer,
    float* __restrict__ denom) {
    uint  T      = sel[0];
    uint  needEq = sel[1];
    float m      = mval[0];
    int lane = threadIdx.x & 63;
    int gw   = blockIdx.x * (256 >> 6) + (threadIdx.x >> 6);
    int nw   = gridDim.x * (256 >> 6);
    float4 np = make_float4(0.f, 0.f, 0.f, 0.f);
    float  dp = 0.f;
    for (int i = gw; i < NN; i += nw) {
        uint k = key[i];
        bool selm;
        if (k > T) {
            selm = true;
        } else if (k == T) {
            uint pos = 0;
            if (lane == 0) pos = atomicAdd(ticket, 1u);
            pos  = __shfl(pos, 0);
            selm = pos < needEq;
        } else {
            selm = false;
        }
        if (!selm) continue;
        float s  = score[i];
        float w  = expf(s * c[i] - m);
        dp += w;
        float  wsc = w * s;
        float4 xv  = *(const float4*)(x + (size_t)i * DD + lane * 4);
        np.x += wsc * xv.x;
        np.y += wsc * xv.y;
        np.z += wsc * xv.z;
        np.w += wsc * xv.w;
    }
    atomAddF(numer + lane * 4 + 0, np.x);
    atomAddF(numer + lane * 4 + 1, np.y);
    atomAddF(numer + lane * 4 + 2, np.z);
    atomAddF(numer + lane * 4 + 3, np.w);
    if (lane == 0) atomAddF(denom, dp);
}

// ---------------- 10. finalize --------------------------------------------
__global__ __launch_bounds__(256) void finalize(
    const float* __restrict__ numer, const float* __restrict__ denom,
    float* __restrict__ out) {
    int i  = threadIdx.x;
    out[i] = numer[i] / denom[0];
}

extern "C" void kernel_launch(void* const* d_in, const int* in_sizes, int n_in,
                              void* d_out, int out_size, void* d_ws, size_t ws_size,
                              hipStream_t stream) {
    const float* h      = (const float*)d_in[0];
    const int*   ei     = (const int*)d_in[1];
    const float* W_l    = (const float*)d_in[2];
    const float* b_l    = (const float*)d_in[3];
    const float* W_r    = (const float*)d_in[4];
    const float* W_rel  = (const float*)d_in[5];
    const float* b_rel  = (const float*)d_in[6];
    const float* W_root = (const float*)d_in[7];
    const float* W_gate = (const float*)d_in[8];
    // b_gate (d_in[9]) cancels in softmax
    float* out = (float*)d_out;

    // ---- workspace layout ----
    ushort* Ab    = (ushort*)d_ws;                    // [NN][512] bf16: [mean|h]
    float*  xbuf  = (float*)(Ab + (size_t)NN * KK);   // N*D f32
    ushort* Wt    = (ushort*)(xbuf + (size_t)NN * DD);// [256][512] bf16
    int*    csr   = (int*)(Wt + (size_t)DD * KK);     // E
    int*    start = csr + NE;                         // N+1
    int*    cursor= start + NN + 1;                   // N
    float*  invdeg= (float*)(cursor + NN);            // N
    float*  score = invdeg + NN;                      // N
    uint*   key   = (uint*)(score + NN);              // N
    // ---- zero-initialized tail (one small memset) ----
    int*    degi  = (int*)(key + NN);                 // N
    float*  y     = (float*)(degi + NN);              // N
    float*  cbuf  = y + NN;                           // N
    float*  rbuf  = cbuf + NN;                        // N
    float*  numer = rbuf + NN;                        // D
    float*  denom = numer + DD;                       // 1
    float*  mval  = denom + 1;                        // 1
    uint*   tick  = (uint*)(mval + 1);                // 1
    uint*   sel   = tick + 1;                         // 2
    size_t zbytes = (size_t)((char*)(sel + 2) - (char*)degi);

    hipMemsetAsync(degi, 0, zbytes, stream);

    count_deg   <<<(NE + 255) / 256, 256, 0, stream>>>(ei, degi);
    scan_start  <<<1, 1024, 0, stream>>>(degi, start, cursor, invdeg);
    fill_csr    <<<(NE + 255) / 256, 256, 0, stream>>>(ei, cursor, csr);
    cast_h      <<<(NN * 64 + 255) / 256, 256, 0, stream>>>(h, Ab);
    cast_W      <<<(KK * DD + 255) / 256, 256, 0, stream>>>(W_l, W_r, Wt);
    gather_mean <<<(NN + 3) / 4, 256, 0, stream>>>(Ab, csr, start, invdeg);
    gemm_x      <<<(NN + 31) / 32, 256, 0, stream>>>(Ab, Wt, b_l,
                                                     W_rel, W_gate, W_root,
                                                     xbuf, y, cbuf, rbuf);
    gather_score<<<(NN * 64 + 255) / 256, 256, 0, stream>>>(y, rbuf, b_rel, csr,
                                                            start, score, key);
    radix_select<<<1, 1024, 0, stream>>>(key, score, cbuf, sel, mval);
    reduce_out  <<<128, 256, 0, stream>>>(xbuf, score, cbuf, key, sel, mval,
                                          tick, numer, denom);
    finalize    <<<1, 256, 0, stream>>>(numer, denom, out);
    (void)n_in; (void)in_sizes; (void)out_size; (void)ws_size;
}